// Round 9
// baseline (447.897 us; speedup 1.0000x reference)
//
#include <hip/hip_runtime.h>

#define N_NODES 100000
#define N_EDGES 1600000
#define D 64
#define N_LAYERS 5
#define FB 1000          // fine buckets (counting sort), bucket = 100 nodes
#define BN 100           // nodes per bucket
#define NX 8             // XCD partitions of the staging array
#define BCAP_X 320       // staging capacity per (xcd,bucket) cell; mean 200,
                         // sigma ~14 -> 8.5 sigma headroom; 320*8B = 64B-mult
#define BCAP 2048        // max records per bucket in sort (mean 1600 + 11s)
#define BIN_BLOCKS 512
#define BIN_THREADS 512
#define BIN_CHUNK 3125   // 512 * 3125 = 1.6M exactly

typedef unsigned short u16;
typedef unsigned long long u64;
typedef __attribute__((ext_vector_type(8))) short bf16x8;
typedef __attribute__((ext_vector_type(4))) float f32x4;

__device__ __forceinline__ float bf2f(u16 u) {
    union { unsigned int i; float f; } v;
    v.i = ((unsigned int)u) << 16;
    return v.f;
}
__device__ __forceinline__ u16 f2bf(float f) {
    union { float f; unsigned int i; } v;
    v.f = f;
    unsigned int r = v.i + 0x7FFFu + ((v.i >> 16) & 1u);  // round-nearest-even
    return (u16)(r >> 16);
}
__device__ __forceinline__ float bf2f_lo(unsigned int pk) {
    union { unsigned int i; float f; } v;
    v.i = pk << 16;
    return v.f;
}
__device__ __forceinline__ float bf2f_hi(unsigned int pk) {
    union { unsigned int i; float f; } v;
    v.i = pk & 0xFFFF0000u;
    return v.f;
}

// ====================== CSR build via 1000-bucket counting sort ==============
// Record = u64: low32 = {(d%100)<<17 | src}, high32 = bits(ew).
// Staging partitioned into 8000 cells = (xcd = blockIdx%8) x bucket so each
// 64B line is written by ONE XCD's L2 only (round-6: WRITE 42 -> ~15MB).

__global__ __launch_bounds__(1024) void initcur_kernel(int* __restrict__ fcur)
{
    int i = blockIdx.x * 1024 + threadIdx.x;
    if (i < NX * FB) fcur[i] = i * BCAP_X;   // fixed-capacity staging cells
}

// Phase 1: bin edges into 1000 fine buckets (by dst/100), staging into this
// block's XCD partition. dst read plain (12.5KB chunk -> pass-2 re-read hits
// L1); src/ew read once, nt (zero reuse); staging stores plain (L2 merge).
__global__ __launch_bounds__(BIN_THREADS) void bin_kernel(
    const int* __restrict__ src, const int* __restrict__ dst,
    const float* __restrict__ ew, int* __restrict__ fcur,
    u64* __restrict__ stag)
{
    __shared__ int hc[FB];
    const int xbase = (blockIdx.x & (NX - 1)) * FB;   // this XCD's cell row
    for (int b = threadIdx.x; b < FB; b += BIN_THREADS) hc[b] = 0;
    __syncthreads();
    const int e0 = blockIdx.x * BIN_CHUNK;
    for (int e = e0 + threadIdx.x; e < e0 + BIN_CHUNK; e += BIN_THREADS) {
        int d = dst[e];
        atomicAdd(&hc[d / BN], 1);
    }
    __syncthreads();
    for (int b = threadIdx.x; b < FB; b += BIN_THREADS) {
        int c = hc[b];
        if (c) hc[b] = atomicAdd(&fcur[xbase + b], c);  // -> global cursor
    }
    __syncthreads();
    for (int e = e0 + threadIdx.x; e < e0 + BIN_CHUNK; e += BIN_THREADS) {
        int d = dst[e];                           // L1-resident re-read
        int b = d / BN;
        int pos = atomicAdd(&hc[b], 1);           // LDS atomic -> global slot
        int s   = __builtin_nontemporal_load(&src[e]);
        float w = __builtin_nontemporal_load(&ew[e]);
        unsigned int pk = (unsigned int)((d - b * BN) << 17) | (unsigned int)s;
        u64 rec = ((u64)(unsigned int)__float_as_int(w) << 32) | pk;
        stag[pos] = rec;                          // plain: L2 write-merge
    }
}

// Exclusive scan of bucket sizes (summing the 8 XCD cells per bucket) ->
// fbase = CSR base per bucket (bucket order == node order).
__global__ __launch_bounds__(1024) void fscan_kernel(
    const int* __restrict__ fcur, int* __restrict__ fbase,
    int* __restrict__ rowptr)
{
    __shared__ int s[1024];
    int t = threadIdx.x;
    int v = 0;
    if (t < FB) {
        #pragma unroll
        for (int x = 0; x < NX; ++x) {
            int cell = x * FB + t;
            v += fcur[cell] - cell * BCAP_X;      // cell size
        }
    }
    s[t] = v;
    __syncthreads();
    for (int off = 1; off < 1024; off <<= 1) {
        int u = (t >= off) ? s[t - off] : 0;
        __syncthreads();
        s[t] += u;
        __syncthreads();
    }
    if (t < FB) fbase[t] = s[t] - v;
    if (t == FB - 1) {
        fbase[FB] = s[t];
        rowptr[N_NODES] = s[t];
    }
}

// Phase 2: one block per bucket. Stream the bucket's 8 XCD sub-segments into
// LDS + 100-counter histogram; tiny scan -> per-node rowptr AND local ranks;
// scatter into the bucket's contiguous ~12.8KB CSR slice (one block = one
// XCD = full-sector writebacks). No global atomics at all.
__global__ __launch_bounds__(256) void sort_kernel(
    const u64* __restrict__ stag, const int* __restrict__ fcur,
    const int* __restrict__ fbase, int* __restrict__ rowptr,
    int2* __restrict__ edges)
{
    __shared__ u64 ls[BCAP];       // 16 KB segment cache
    __shared__ int cnt[BN];
    __shared__ int cur[BN];
    __shared__ int sc[128];
    const int b = blockIdx.x;
    const int base = fbase[b];
    const int t = threadIdx.x;
    for (int i = t; i < BN; i += 256) cnt[i] = 0;
    __syncthreads();
    int ofs = 0;
    #pragma unroll
    for (int x = 0; x < NX; ++x) {
        int cell = x * FB + b;
        int sz = fcur[cell] - cell * BCAP_X;      // uniform scalar load
        const u64* sp = stag + (size_t)cell * BCAP_X;
        for (int i = t; i < sz; i += 256) {
            u64 r = __builtin_nontemporal_load(&sp[i]);
            ls[ofs + i] = r;
            atomicAdd(&cnt[((unsigned int)r) >> 17], 1);
        }
        ofs += sz;
    }
    const int size = ofs;
    __syncthreads();
    if (t < 128) sc[t] = (t < BN) ? cnt[t] : 0;
    __syncthreads();
    for (int off = 1; off < 128; off <<= 1) {
        int u = 0;
        if (t < 128 && t >= off) u = sc[t - off];
        __syncthreads();
        if (t < 128) sc[t] += u;
        __syncthreads();
    }
    if (t < BN) {
        int excl = sc[t] - cnt[t];
        rowptr[b * BN + t] = base + excl;
        cur[t] = excl;
    }
    __syncthreads();
    for (int i = t; i < size; i += 256) {
        u64 r = ls[i];
        unsigned int lo = (unsigned int)r;
        int dloc = lo >> 17;
        int rank = atomicAdd(&cur[dloc], 1);
        edges[base + rank] = make_int2((int)(lo & 0x1FFFFu),
                                       (int)(unsigned int)(r >> 32));
    }
}

// ======================= f32 -> bf16 convert (input x) =======================
__global__ __launch_bounds__(256) void f2bf_kernel(
    const float* __restrict__ in, u16* __restrict__ out)
{
    int i = blockIdx.x * 256 + threadIdx.x;   // one float4 per thread
    if (i >= (N_NODES * D) / 4) return;
    float4 v = ((const float4*)in)[i];
    ushort4 o;
    o.x = f2bf(v.x); o.y = f2bf(v.y); o.z = f2bf(v.z); o.w = f2bf(v.w);
    ((ushort4*)out)[i] = o;
}

// ================== Weight prep: W2T[l][n][k] bf16, k = [Wrel;Wroot] =========
__global__ __launch_bounds__(256) void wprep_kernel(
    const float* __restrict__ Wrel, const float* __restrict__ Wroot,
    u16* __restrict__ W2T)
{
    int i = blockIdx.x * 256 + threadIdx.x;  // over 5*64*128
    if (i >= N_LAYERS * 64 * 128) return;
    int l = i / (64 * 128);
    int rem = i % (64 * 128);
    int n = rem >> 7;   // out dim
    int k = rem & 127;  // input dim (0..63 = rel/agg, 64..127 = root/x)
    float v = (k < 64) ? Wrel[l * 4096 + k * 64 + n]
                       : Wroot[l * 4096 + (k - 64) * 64 + n];
    W2T[i] = f2bf(v);
}

// ============ Fused layer v3: scalar edge stream, 1 node/wave ================
// Round-8 analysis: 84 cyc/edge measured vs ~20 issue-bound -> latency-
// dominated, and the inner loop wastes 16 ds_bpermute per 8 edges (the
// __shfl broadcasts) because edge records travel through VGPRs. v3: ONE
// node per wave -> the node's CSR segment address is wave-uniform -> edge
// records come in via the SCALAR pipe (s_load, free broadcast), zero
// shuffles. Lanes: eo=lane>>5 picks edge (2j+eo), sl=lane&31 picks dim pair
// -> one global_load_dword gathers TWO edges' rows (4 lines). Halves merge
// with a single shfl_xor(32) at the end. Block = 1024 thr = 16 waves = one
// MFMA A-tile; 100K gather waves (2x round 8), 28-40 VGPR -> 2 blocks/CU.
// Phase B (waves 0-3) identical to round 8 (HW-verified).
__global__ __launch_bounds__(1024) void layer_kernel(
    const u16* __restrict__ hin, const int* __restrict__ rowptr,
    const int2* __restrict__ edges, const u16* __restrict__ W2T,
    const float* __restrict__ brel,
    u16* __restrict__ hout_bf, float* __restrict__ hout_f32, int relu)
{
    __shared__ u16 aggs[16][64];      // 2KB [node][dim], rows XOR-swizzled
    const int wave = threadIdx.x >> 6;
    const int lane = threadIdx.x & 63;
    const int nb16 = blockIdx.x * 16;
    const int sl   = lane & 31;       // dim pair -> dims 2sl, 2sl+1
    const int eo   = lane >> 5;       // which edge of the current pair

    // ---- Phase A: this wave aggregates node nb16+wave ----
    {
        const int node = nb16 + wave;
        const int b = __builtin_amdgcn_readfirstlane(rowptr[node]);
        const int e = __builtin_amdgcn_readfirstlane(rowptr[node + 1]);
        const u64* eseg = (const u64*)edges;   // record: lo=src, hi=ew bits
        float acc0 = 0.f, acc1 = 0.f;
        int j = b;

        #define PAIR(ra, rb) {                                               \
            int   s_ = (int)(unsigned int)(eo ? (rb) : (ra));                \
            float w_ = __int_as_float((int)(unsigned int)                    \
                                      ((eo ? (rb) : (ra)) >> 32));           \
            unsigned int p_ = *(const unsigned int*)                         \
                              (hin + ((size_t)s_ << 6) + sl * 2);            \
            acc0 += bf2f_lo(p_) * w_;                                        \
            acc1 += bf2f_hi(p_) * w_; }

        for (; j + 8 <= e; j += 8) {          // 8 records via scalar loads
            u64 r0 = eseg[j + 0], r1 = eseg[j + 1];
            u64 r2 = eseg[j + 2], r3 = eseg[j + 3];
            u64 r4 = eseg[j + 4], r5 = eseg[j + 5];
            u64 r6 = eseg[j + 6], r7 = eseg[j + 7];
            PAIR(r0, r1); PAIR(r2, r3); PAIR(r4, r5); PAIR(r6, r7);
        }
        for (; j + 2 <= e; j += 2) {
            u64 ra = eseg[j], rb = eseg[j + 1];
            PAIR(ra, rb);
        }
        if (j < e) {                           // odd tail: half-wave only
            u64 ra = eseg[j];
            if (eo == 0) {
                int   s_ = (int)(unsigned int)ra;
                float w_ = __int_as_float((int)(unsigned int)(ra >> 32));
                unsigned int p_ = *(const unsigned int*)
                                  (hin + ((size_t)s_ << 6) + sl * 2);
                acc0 += bf2f_lo(p_) * w_;
                acc1 += bf2f_hi(p_) * w_;
            }
        }
        #undef PAIR

        acc0 += __shfl_xor(acc0, 32);          // merge the two halves
        acc1 += __shfl_xor(acc1, 32);
        if (eo == 0) {
            // dims (2sl, 2sl+1) of row `wave`, XOR-swizzled within the row
            int u16idx = (wave << 6) | ((sl * 2) ^ ((wave & 7) << 3));
            unsigned int o = ((unsigned int)f2bf(acc1) << 16) | f2bf(acc0);
            *(unsigned int*)(&aggs[0][0] + u16idx) = o;
        }
    }
    __syncthreads();

    // ---- Phase B: waves 0-3, wave = n-tile. A = [agg ; hin_own] @ W2T + b --
    if (wave < 4) {
        const int nt = wave;
        const int m = lane & 15;   // node-in-tile for A; out-dim for B/D
        const int q = lane >> 4;   // quad

        bf16x8 a[4];
        {
            int r0 = (m << 6) | ((q * 8) ^ ((m & 7) << 3));        // dims 8q..
            int r1 = (m << 6) | ((32 + q * 8) ^ ((m & 7) << 3));   // 32+8q..
            a[0] = *(const bf16x8*)(&aggs[0][0] + r0);   // k  0..31 (agg)
            a[1] = *(const bf16x8*)(&aggs[0][0] + r1);   // k 32..63 (agg)
        }
        size_t rowa = (size_t)(nb16 + m) << 6;
        a[2] = *(const bf16x8*)(hin + rowa + q * 8);        // k 64..95 (x)
        a[3] = *(const bf16x8*)(hin + rowa + 32 + q * 8);   // k 96..127 (x)

        bf16x8 bfr[4];
        #pragma unroll
        for (int kk = 0; kk < 4; ++kk)
            bfr[kk] = *(const bf16x8*)(W2T + (size_t)(nt * 16 + m) * 128
                                       + kk * 32 + q * 8);

        float bv = brel[nt * 16 + m];
        f32x4 acc = (f32x4){bv, bv, bv, bv};
        #pragma unroll
        for (int kk = 0; kk < 4; ++kk)
            acc = __builtin_amdgcn_mfma_f32_16x16x32_bf16(a[kk], bfr[kk],
                                                          acc, 0, 0, 0);

        #pragma unroll
        for (int r = 0; r < 4; ++r) {
            int n2 = nb16 + q * 4 + r;           // node (row of D)
            float v = acc[r];
            if (relu) v = fmaxf(v, 0.f);
            int dim = nt * 16 + m;               // out dim (col of D)
            if (hout_f32) hout_f32[(size_t)n2 * 64 + dim] = v;
            else          hout_bf [(size_t)n2 * 64 + dim] = f2bf(v);
        }
    }
}

extern "C" void kernel_launch(void* const* d_in, const int* in_sizes, int n_in,
                              void* d_out, int out_size, void* d_ws, size_t ws_size,
                              hipStream_t stream)
{
    const float* x     = (const float*)d_in[0];
    const int*   ei    = (const int*)d_in[1];   // [2, E] int32
    const float* ew    = (const float*)d_in[2];
    const float* Wrel  = (const float*)d_in[3]; // [5, 64, 64]
    const float* brel  = (const float*)d_in[4]; // [5, 64]
    const float* Wroot = (const float*)d_in[5]; // [5, 64, 64]
    float* out = (float*)d_out;

    const int* src = ei;
    const int* dst = ei + N_EDGES;

    const size_t featb_bytes = (size_t)N_NODES * D * 2;  // 12.8 MB bf16
    char* ws = (char*)d_ws;
    size_t off = 0;
    u16*  hb     = (u16*)(ws + off);  off += featb_bytes;   // ping
    u16*  hb2    = (u16*)(ws + off);  off += featb_bytes;   // pong
    u16*  W2T    = (u16*)(ws + off);  off += (size_t)N_LAYERS * 64 * 128 * 2;
    int*  rowptr = (int*)(ws + off);  off += 400016;
    int*  fcur   = (int*)(ws + off);  off += NX * FB * 4;
    int*  fbase  = (int*)(ws + off);  off += (FB + 1) * 4 + 60;
    int2* edges  = (int2*)(ws + off); off += (size_t)N_EDGES * 8;

    // stag aliases hb+hb2 (8000 cells * 320 * 8B = 20.48MB < 25.6MB): live
    // only bin -> sort, both complete (stream-ordered) before f2bf writes hb.
    u64* stag = (u64*)ws;

    u16* hbuf[2] = {hb, hb2};

    const int cblocks = (N_NODES * D / 4 + 255) / 256;
    const int wblocks = (N_LAYERS * 64 * 128 + 255) / 256;  // 160
    const int lblocks = N_NODES / 16;                // 6250 (16 nodes/block)

    // ---- CSR build (counting sort) + converts ----
    initcur_kernel<<<8, 1024, 0, stream>>>(fcur);
    bin_kernel<<<BIN_BLOCKS, BIN_THREADS, 0, stream>>>(src, dst, ew, fcur, stag);
    fscan_kernel<<<1, 1024, 0, stream>>>(fcur, fbase, rowptr);
    sort_kernel<<<FB, 256, 0, stream>>>(stag, fcur, fbase, rowptr, edges);
    f2bf_kernel<<<cblocks, 256, 0, stream>>>(x, hb);
    wprep_kernel<<<wblocks, 256, 0, stream>>>(Wrel, Wroot, W2T);

    // ---- 5 fused GraphConv layers (ping-pong h buffers) ----
    for (int layer = 0; layer < N_LAYERS; ++layer) {
        int last = (layer == N_LAYERS - 1);
        layer_kernel<<<lblocks, 1024, 0, stream>>>(
            hbuf[layer & 1], rowptr, edges,
            W2T + (size_t)layer * 64 * 128,
            brel + (size_t)layer * D,
            last ? nullptr : hbuf[(layer + 1) & 1],
            last ? out : nullptr,
            last ? 0 : 1);
    }
}

// Round 11
// 444.580 us; speedup vs baseline: 1.0075x; 1.0075x over previous
//
#include <hip/hip_runtime.h>

#define N_NODES 100000
#define N_EDGES 1600000
#define D 64
#define N_LAYERS 5
#define FB 1000          // fine buckets (counting sort), bucket = 100 nodes
#define BN 100           // nodes per bucket
#define NX 8             // XCD partitions of the staging array
#define BCAP_X 320       // staging capacity per (xcd,bucket) cell; mean 200,
                         // sigma ~14 -> 8.5 sigma headroom; 320*8B = 64B-mult
#define BCAP 2048        // max records per bucket in sort (mean 1600 + 11s)
#define BIN_BLOCKS 512
#define BIN_THREADS 512
#define BIN_CHUNK 3125   // 512 * 3125 = 1.6M exactly

typedef unsigned short u16;
typedef unsigned long long u64;
typedef __attribute__((ext_vector_type(8))) short bf16x8;
typedef __attribute__((ext_vector_type(4))) float f32x4;

__device__ __forceinline__ float bf2f(u16 u) {
    union { unsigned int i; float f; } v;
    v.i = ((unsigned int)u) << 16;
    return v.f;
}
__device__ __forceinline__ u16 f2bf(float f) {
    union { float f; unsigned int i; } v;
    v.f = f;
    unsigned int r = v.i + 0x7FFFu + ((v.i >> 16) & 1u);  // round-nearest-even
    return (u16)(r >> 16);
}
__device__ __forceinline__ float bf2f_lo(unsigned int pk) {
    union { unsigned int i; float f; } v;
    v.i = pk << 16;
    return v.f;
}
__device__ __forceinline__ float bf2f_hi(unsigned int pk) {
    union { unsigned int i; float f; } v;
    v.i = pk & 0xFFFF0000u;
    return v.f;
}

// ====================== CSR build via 1000-bucket counting sort ==============
// Record = u64: low32 = {(d%100)<<17 | src}, high32 = bits(ew).
// Staging partitioned into 8000 cells = (xcd = blockIdx%8) x bucket so each
// 64B line is written by ONE XCD's L2 only (round-6: WRITE 42 -> ~15MB).

__global__ __launch_bounds__(1024) void initcur_kernel(int* __restrict__ fcur)
{
    int i = blockIdx.x * 1024 + threadIdx.x;
    if (i < NX * FB) fcur[i] = i * BCAP_X;   // fixed-capacity staging cells
}

// Phase 1: bin edges into 1000 fine buckets (by dst/100), staging into this
// block's XCD partition. dst read plain (12.5KB chunk -> pass-2 re-read hits
// L1); src/ew read once, nt (zero reuse); staging stores plain (L2 merge).
__global__ __launch_bounds__(BIN_THREADS) void bin_kernel(
    const int* __restrict__ src, const int* __restrict__ dst,
    const float* __restrict__ ew, int* __restrict__ fcur,
    u64* __restrict__ stag)
{
    __shared__ int hc[FB];
    const int xbase = (blockIdx.x & (NX - 1)) * FB;   // this XCD's cell row
    for (int b = threadIdx.x; b < FB; b += BIN_THREADS) hc[b] = 0;
    __syncthreads();
    const int e0 = blockIdx.x * BIN_CHUNK;
    for (int e = e0 + threadIdx.x; e < e0 + BIN_CHUNK; e += BIN_THREADS) {
        int d = dst[e];
        atomicAdd(&hc[d / BN], 1);
    }
    __syncthreads();
    for (int b = threadIdx.x; b < FB; b += BIN_THREADS) {
        int c = hc[b];
        if (c) hc[b] = atomicAdd(&fcur[xbase + b], c);  // -> global cursor
    }
    __syncthreads();
    for (int e = e0 + threadIdx.x; e < e0 + BIN_CHUNK; e += BIN_THREADS) {
        int d = dst[e];                           // L1-resident re-read
        int b = d / BN;
        int pos = atomicAdd(&hc[b], 1);           // LDS atomic -> global slot
        int s   = __builtin_nontemporal_load(&src[e]);
        float w = __builtin_nontemporal_load(&ew[e]);
        unsigned int pk = (unsigned int)((d - b * BN) << 17) | (unsigned int)s;
        u64 rec = ((u64)(unsigned int)__float_as_int(w) << 32) | pk;
        stag[pos] = rec;                          // plain: L2 write-merge
    }
}

// Exclusive scan of bucket sizes (summing the 8 XCD cells per bucket) ->
// fbase = CSR base per bucket (bucket order == node order).
__global__ __launch_bounds__(1024) void fscan_kernel(
    const int* __restrict__ fcur, int* __restrict__ fbase,
    int* __restrict__ rowptr)
{
    __shared__ int s[1024];
    int t = threadIdx.x;
    int v = 0;
    if (t < FB) {
        #pragma unroll
        for (int x = 0; x < NX; ++x) {
            int cell = x * FB + t;
            v += fcur[cell] - cell * BCAP_X;      // cell size
        }
    }
    s[t] = v;
    __syncthreads();
    for (int off = 1; off < 1024; off <<= 1) {
        int u = (t >= off) ? s[t - off] : 0;
        __syncthreads();
        s[t] += u;
        __syncthreads();
    }
    if (t < FB) fbase[t] = s[t] - v;
    if (t == FB - 1) {
        fbase[FB] = s[t];
        rowptr[N_NODES] = s[t];
    }
}

// Phase 2: one block per bucket. Stream the bucket's 8 XCD sub-segments into
// LDS + 100-counter histogram; tiny scan -> per-node rowptr AND local ranks;
// scatter into the bucket's contiguous ~12.8KB CSR slice (one block = one
// XCD = full-sector writebacks). No global atomics at all.
__global__ __launch_bounds__(256) void sort_kernel(
    const u64* __restrict__ stag, const int* __restrict__ fcur,
    const int* __restrict__ fbase, int* __restrict__ rowptr,
    int2* __restrict__ edges)
{
    __shared__ u64 ls[BCAP];       // 16 KB segment cache
    __shared__ int cnt[BN];
    __shared__ int cur[BN];
    __shared__ int sc[128];
    const int b = blockIdx.x;
    const int base = fbase[b];
    const int t = threadIdx.x;
    for (int i = t; i < BN; i += 256) cnt[i] = 0;
    __syncthreads();
    int ofs = 0;
    #pragma unroll
    for (int x = 0; x < NX; ++x) {
        int cell = x * FB + b;
        int sz = fcur[cell] - cell * BCAP_X;      // uniform scalar load
        const u64* sp = stag + (size_t)cell * BCAP_X;
        for (int i = t; i < sz; i += 256) {
            u64 r = __builtin_nontemporal_load(&sp[i]);
            ls[ofs + i] = r;
            atomicAdd(&cnt[((unsigned int)r) >> 17], 1);
        }
        ofs += sz;
    }
    const int size = ofs;
    __syncthreads();
    if (t < 128) sc[t] = (t < BN) ? cnt[t] : 0;
    __syncthreads();
    for (int off = 1; off < 128; off <<= 1) {
        int u = 0;
        if (t < 128 && t >= off) u = sc[t - off];
        __syncthreads();
        if (t < 128) sc[t] += u;
        __syncthreads();
    }
    if (t < BN) {
        int excl = sc[t] - cnt[t];
        rowptr[b * BN + t] = base + excl;
        cur[t] = excl;
    }
    __syncthreads();
    for (int i = t; i < size; i += 256) {
        u64 r = ls[i];
        unsigned int lo = (unsigned int)r;
        int dloc = lo >> 17;
        int rank = atomicAdd(&cur[dloc], 1);
        edges[base + rank] = make_int2((int)(lo & 0x1FFFFu),
                                       (int)(unsigned int)(r >> 32));
    }
}

// ======================= f32 -> bf16 convert (input x) =======================
__global__ __launch_bounds__(256) void f2bf_kernel(
    const float* __restrict__ in, u16* __restrict__ out)
{
    int i = blockIdx.x * 256 + threadIdx.x;   // one float4 per thread
    if (i >= (N_NODES * D) / 4) return;
    float4 v = ((const float4*)in)[i];
    ushort4 o;
    o.x = f2bf(v.x); o.y = f2bf(v.y); o.z = f2bf(v.z); o.w = f2bf(v.w);
    ((ushort4*)out)[i] = o;
}

// ================== Weight prep: W2T[l][n][k] bf16, k = [Wrel;Wroot] =========
__global__ __launch_bounds__(256) void wprep_kernel(
    const float* __restrict__ Wrel, const float* __restrict__ Wroot,
    u16* __restrict__ W2T)
{
    int i = blockIdx.x * 256 + threadIdx.x;  // over 5*64*128
    if (i >= N_LAYERS * 64 * 128) return;
    int l = i / (64 * 128);
    int rem = i % (64 * 128);
    int n = rem >> 7;   // out dim
    int k = rem & 127;  // input dim (0..63 = rel/agg, 64..127 = root/x)
    float v = (k < 64) ? Wrel[l * 4096 + k * 64 + n]
                       : Wroot[l * 4096 + (k - 64) * 64 + n];
    W2T[i] = f2bf(v);
}

// ====== Fused layer v4: round-8 structure + depth-2 pipelined gather =========
// Round-9 post-mortem: scalar edge stream regressed (s_load serial lgkm stall
// + halved loads-in-flight). REVERTED to round-8 (2 nodes/wave, shfl
// broadcasts; 55.4us, 63% occ). Round-8 arithmetic: 21 cyc/edge/CU vs ~3.5
// instr/edge -> issue port ~17% busy -> memory-latency-stalled. The rolled
// j-loop exposes a full L2/L3 round trip per 8-edge group (bpermute -> load
// -> vmcnt-wait -> consume, strictly in order; compiler can't pipeline a
// dynamic-trip rolled loop). v4: fully unroll the <=4 groups per 32-edge
// chunk, software-pipeline depth 2 with named A/B register groups (all
// compile-time indices): issue A, issue B, consume A, fetch A', consume B...
// -> 16 gathers in flight instead of 8, exposed latency halved.
// (Round-10 run died on broker infra before measuring; resubmitted as-is.)
#define GDECL(G) unsigned int G##p0,G##p1,G##p2,G##p3,G##p4,G##p5,G##p6,G##p7; \
                 float G##w0,G##w1,G##w2,G##w3,G##w4,G##w5,G##w6,G##w7
#define GFETCH(G, jb) {                                                     \
    int s0_=__shfl(idx,(jb)+0,32), s1_=__shfl(idx,(jb)+1,32),               \
        s2_=__shfl(idx,(jb)+2,32), s3_=__shfl(idx,(jb)+3,32),               \
        s4_=__shfl(idx,(jb)+4,32), s5_=__shfl(idx,(jb)+5,32),               \
        s6_=__shfl(idx,(jb)+6,32), s7_=__shfl(idx,(jb)+7,32);               \
    G##w0=__shfl(wv,(jb)+0,32); G##w1=__shfl(wv,(jb)+1,32);                 \
    G##w2=__shfl(wv,(jb)+2,32); G##w3=__shfl(wv,(jb)+3,32);                 \
    G##w4=__shfl(wv,(jb)+4,32); G##w5=__shfl(wv,(jb)+5,32);                 \
    G##w6=__shfl(wv,(jb)+6,32); G##w7=__shfl(wv,(jb)+7,32);                 \
    G##p0=*(const unsigned int*)(hin+((size_t)s0_<<6)+sl*2);                \
    G##p1=*(const unsigned int*)(hin+((size_t)s1_<<6)+sl*2);                \
    G##p2=*(const unsigned int*)(hin+((size_t)s2_<<6)+sl*2);                \
    G##p3=*(const unsigned int*)(hin+((size_t)s3_<<6)+sl*2);                \
    G##p4=*(const unsigned int*)(hin+((size_t)s4_<<6)+sl*2);                \
    G##p5=*(const unsigned int*)(hin+((size_t)s5_<<6)+sl*2);                \
    G##p6=*(const unsigned int*)(hin+((size_t)s6_<<6)+sl*2);                \
    G##p7=*(const unsigned int*)(hin+((size_t)s7_<<6)+sl*2); }
#define GCONS(G)                                                            \
    acc0 += bf2f_lo(G##p0)*G##w0 + bf2f_lo(G##p1)*G##w1                     \
          + bf2f_lo(G##p2)*G##w2 + bf2f_lo(G##p3)*G##w3                     \
          + bf2f_lo(G##p4)*G##w4 + bf2f_lo(G##p5)*G##w5                     \
          + bf2f_lo(G##p6)*G##w6 + bf2f_lo(G##p7)*G##w7;                    \
    acc1 += bf2f_hi(G##p0)*G##w0 + bf2f_hi(G##p1)*G##w1                     \
          + bf2f_hi(G##p2)*G##w2 + bf2f_hi(G##p3)*G##w3                     \
          + bf2f_hi(G##p4)*G##w4 + bf2f_hi(G##p5)*G##w5                     \
          + bf2f_hi(G##p6)*G##w6 + bf2f_hi(G##p7)*G##w7

__global__ __launch_bounds__(512, 4) void layer_kernel(
    const u16* __restrict__ hin, const int* __restrict__ rowptr,
    const int2* __restrict__ edges, const u16* __restrict__ W2T,
    const float* __restrict__ brel,
    u16* __restrict__ hout_bf, float* __restrict__ hout_f32, int relu)
{
    __shared__ u16 aggs[16][64];      // 2KB [node][dim], rows XOR-swizzled
    const int wave = threadIdx.x >> 6;
    const int lane = threadIdx.x & 63;
    const int nb16 = blockIdx.x * 16;
    const int sl   = lane & 31;       // sublane: dim pair -> dims 2sl, 2sl+1
    const int half = lane >> 5;

    // ---- Phase A: this wave aggregates nodes nb16+2*wave, nb16+2*wave+1 ----
    {
        int nl = 2 * wave + half;         // node-local 0..15 (exact fit)
        int node = nb16 + nl;
        float acc0 = 0.f, acc1 = 0.f;
        int b = rowptr[node];
        int e = rowptr[node + 1];
        GDECL(A); GDECL(B);
        for (int base = b; base < e; base += 32) {
            int cnt = min(32, e - base);
            int idx = 0;
            float wv = 0.f;
            if (sl < cnt) {
                int2 p = edges[base + sl];   // per-half coalesced 256B
                idx = p.x;
                wv = __int_as_float(p.y);
            }
            int grps = cnt >> 3;             // full groups of 8 (0..4)
            if (grps > 0) GFETCH(A, 0);      // issue A (8 loads in flight)
            if (grps > 1) GFETCH(B, 8);      // issue B (16 in flight)
            if (grps > 0) { GCONS(A); }      // consume A under B's latency
            if (grps > 2) GFETCH(A, 16);     // refill A
            if (grps > 1) { GCONS(B); }
            if (grps > 3) GFETCH(B, 24);
            if (grps > 2) { GCONS(A); }
            if (grps > 3) { GCONS(B); }
            for (int j = grps << 3; j < cnt; ++j) {   // tail < 8 edges
                int s = __shfl(idx, j, 32);
                float w = __shfl(wv, j, 32);
                unsigned int pk = *(const unsigned int*)(hin + ((size_t)s << 6) + sl * 2);
                acc0 += bf2f_lo(pk) * w;
                acc1 += bf2f_hi(pk) * w;
            }
        }
        // dims (2sl, 2sl+1) of row nl, XOR-swizzled within the row
        int u16idx = (nl << 6) | ((sl * 2) ^ ((nl & 7) << 3));
        unsigned int o = ((unsigned int)f2bf(acc1) << 16) | f2bf(acc0);
        *(unsigned int*)(&aggs[0][0] + u16idx) = o;
    }
    __syncthreads();

    // ---- Phase B: waves 0-3, wave = n-tile. A = [agg ; hin_own] @ W2T + b --
    if (wave < 4) {
        const int nt = wave;
        const int m = lane & 15;   // node-in-tile for A; out-dim for B/D
        const int q = lane >> 4;   // quad

        bf16x8 a[4];
        {
            int r0 = (m << 6) | ((q * 8) ^ ((m & 7) << 3));        // dims 8q..
            int r1 = (m << 6) | ((32 + q * 8) ^ ((m & 7) << 3));   // 32+8q..
            a[0] = *(const bf16x8*)(&aggs[0][0] + r0);   // k  0..31 (agg)
            a[1] = *(const bf16x8*)(&aggs[0][0] + r1);   // k 32..63 (agg)
        }
        size_t rowa = (size_t)(nb16 + m) << 6;
        a[2] = *(const bf16x8*)(hin + rowa + q * 8);        // k 64..95 (x)
        a[3] = *(const bf16x8*)(hin + rowa + 32 + q * 8);   // k 96..127 (x)

        bf16x8 bfr[4];
        #pragma unroll
        for (int kk = 0; kk < 4; ++kk)
            bfr[kk] = *(const bf16x8*)(W2T + (size_t)(nt * 16 + m) * 128
                                       + kk * 32 + q * 8);

        float bv = brel[nt * 16 + m];
        f32x4 acc = (f32x4){bv, bv, bv, bv};
        #pragma unroll
        for (int kk = 0; kk < 4; ++kk)
            acc = __builtin_amdgcn_mfma_f32_16x16x32_bf16(a[kk], bfr[kk],
                                                          acc, 0, 0, 0);

        #pragma unroll
        for (int r = 0; r < 4; ++r) {
            int n2 = nb16 + q * 4 + r;           // node (row of D)
            float v = acc[r];
            if (relu) v = fmaxf(v, 0.f);
            int dim = nt * 16 + m;               // out dim (col of D)
            if (hout_f32) hout_f32[(size_t)n2 * 64 + dim] = v;
            else          hout_bf [(size_t)n2 * 64 + dim] = f2bf(v);
        }
    }
}

extern "C" void kernel_launch(void* const* d_in, const int* in_sizes, int n_in,
                              void* d_out, int out_size, void* d_ws, size_t ws_size,
                              hipStream_t stream)
{
    const float* x     = (const float*)d_in[0];
    const int*   ei    = (const int*)d_in[1];   // [2, E] int32
    const float* ew    = (const float*)d_in[2];
    const float* Wrel  = (const float*)d_in[3]; // [5, 64, 64]
    const float* brel  = (const float*)d_in[4]; // [5, 64]
    const float* Wroot = (const float*)d_in[5]; // [5, 64, 64]
    float* out = (float*)d_out;

    const int* src = ei;
    const int* dst = ei + N_EDGES;

    const size_t featb_bytes = (size_t)N_NODES * D * 2;  // 12.8 MB bf16
    char* ws = (char*)d_ws;
    size_t off = 0;
    u16*  hb     = (u16*)(ws + off);  off += featb_bytes;   // ping
    u16*  hb2    = (u16*)(ws + off);  off += featb_bytes;   // pong
    u16*  W2T    = (u16*)(ws + off);  off += (size_t)N_LAYERS * 64 * 128 * 2;
    int*  rowptr = (int*)(ws + off);  off += 400016;
    int*  fcur   = (int*)(ws + off);  off += NX * FB * 4;
    int*  fbase  = (int*)(ws + off);  off += (FB + 1) * 4 + 60;
    int2* edges  = (int2*)(ws + off); off += (size_t)N_EDGES * 8;

    // stag aliases hb+hb2 (8000 cells * 320 * 8B = 20.48MB < 25.6MB): live
    // only bin -> sort, both complete (stream-ordered) before f2bf writes hb.
    u64* stag = (u64*)ws;

    u16* hbuf[2] = {hb, hb2};

    const int cblocks = (N_NODES * D / 4 + 255) / 256;
    const int wblocks = (N_LAYERS * 64 * 128 + 255) / 256;  // 160
    const int lblocks = N_NODES / 16;                // 6250 (16 nodes/block)

    // ---- CSR build (counting sort) + converts ----
    initcur_kernel<<<8, 1024, 0, stream>>>(fcur);
    bin_kernel<<<BIN_BLOCKS, BIN_THREADS, 0, stream>>>(src, dst, ew, fcur, stag);
    fscan_kernel<<<1, 1024, 0, stream>>>(fcur, fbase, rowptr);
    sort_kernel<<<FB, 256, 0, stream>>>(stag, fcur, fbase, rowptr, edges);
    f2bf_kernel<<<cblocks, 256, 0, stream>>>(x, hb);
    wprep_kernel<<<wblocks, 256, 0, stream>>>(Wrel, Wroot, W2T);

    // ---- 5 fused GraphConv layers (ping-pong h buffers) ----
    for (int layer = 0; layer < N_LAYERS; ++layer) {
        int last = (layer == N_LAYERS - 1);
        layer_kernel<<<lblocks, 512, 0, stream>>>(
            hbuf[layer & 1], rowptr, edges,
            W2T + (size_t)layer * 64 * 128,
            brel + (size_t)layer * D,
            last ? nullptr : hbuf[(layer + 1) & 1],
            last ? out : nullptr,
            last ? 0 : 1);
    }
}

// Round 12
// 390.406 us; speedup vs baseline: 1.1473x; 1.1388x over previous
//
#include <hip/hip_runtime.h>

#define N_NODES 100000
#define N_EDGES 1600000
#define D 64
#define N_LAYERS 5
#define FB 1000          // fine buckets (counting sort), bucket = 100 nodes
#define BN 100           // nodes per bucket
#define NX 8             // XCD partitions of the staging array
#define BCAP_X 320       // staging capacity per (xcd,bucket) cell; mean 200,
                         // sigma ~14 -> 8.5 sigma headroom; 320*8B = 64B-mult
#define BCAP 2048        // max records per bucket in sort (mean 1600 + 11s)
#define BIN_BLOCKS 512
#define BIN_THREADS 512
#define BIN_CHUNK 3125   // 512 * 3125 = 1.6M exactly

typedef unsigned short u16;
typedef unsigned long long u64;
typedef __attribute__((ext_vector_type(8))) short bf16x8;
typedef __attribute__((ext_vector_type(4))) float f32x4;

__device__ __forceinline__ float bf2f(u16 u) {
    union { unsigned int i; float f; } v;
    v.i = ((unsigned int)u) << 16;
    return v.f;
}
__device__ __forceinline__ u16 f2bf(float f) {
    union { float f; unsigned int i; } v;
    v.f = f;
    unsigned int r = v.i + 0x7FFFu + ((v.i >> 16) & 1u);  // round-nearest-even
    return (u16)(r >> 16);
}
__device__ __forceinline__ float bf2f_lo(unsigned int pk) {
    union { unsigned int i; float f; } v;
    v.i = pk << 16;
    return v.f;
}
__device__ __forceinline__ float bf2f_hi(unsigned int pk) {
    union { unsigned int i; float f; } v;
    v.i = pk & 0xFFFF0000u;
    return v.f;
}

// ====================== CSR build via 1000-bucket counting sort ==============
// Record = u64: low32 = {(d%100)<<17 | src}, high32 = bits(ew).
// Staging partitioned into 8000 cells = (xcd = blockIdx%8) x bucket so each
// 64B line is written by ONE XCD's L2 only (round-6: WRITE 42 -> ~15MB).

__global__ __launch_bounds__(1024) void initcur_kernel(int* __restrict__ fcur)
{
    int i = blockIdx.x * 1024 + threadIdx.x;
    if (i < NX * FB) fcur[i] = i * BCAP_X;   // fixed-capacity staging cells
}

// Phase 1: bin edges into 1000 fine buckets (by dst/100), staging into this
// block's XCD partition. dst read plain (12.5KB chunk -> pass-2 re-read hits
// L1); src/ew read once, nt (zero reuse); staging stores plain (L2 merge).
__global__ __launch_bounds__(BIN_THREADS) void bin_kernel(
    const int* __restrict__ src, const int* __restrict__ dst,
    const float* __restrict__ ew, int* __restrict__ fcur,
    u64* __restrict__ stag)
{
    __shared__ int hc[FB];
    const int xbase = (blockIdx.x & (NX - 1)) * FB;   // this XCD's cell row
    for (int b = threadIdx.x; b < FB; b += BIN_THREADS) hc[b] = 0;
    __syncthreads();
    const int e0 = blockIdx.x * BIN_CHUNK;
    for (int e = e0 + threadIdx.x; e < e0 + BIN_CHUNK; e += BIN_THREADS) {
        int d = dst[e];
        atomicAdd(&hc[d / BN], 1);
    }
    __syncthreads();
    for (int b = threadIdx.x; b < FB; b += BIN_THREADS) {
        int c = hc[b];
        if (c) hc[b] = atomicAdd(&fcur[xbase + b], c);  // -> global cursor
    }
    __syncthreads();
    for (int e = e0 + threadIdx.x; e < e0 + BIN_CHUNK; e += BIN_THREADS) {
        int d = dst[e];                           // L1-resident re-read
        int b = d / BN;
        int pos = atomicAdd(&hc[b], 1);           // LDS atomic -> global slot
        int s   = __builtin_nontemporal_load(&src[e]);
        float w = __builtin_nontemporal_load(&ew[e]);
        unsigned int pk = (unsigned int)((d - b * BN) << 17) | (unsigned int)s;
        u64 rec = ((u64)(unsigned int)__float_as_int(w) << 32) | pk;
        stag[pos] = rec;                          // plain: L2 write-merge
    }
}

// Exclusive scan of bucket sizes (summing the 8 XCD cells per bucket) ->
// fbase = CSR base per bucket (bucket order == node order).
__global__ __launch_bounds__(1024) void fscan_kernel(
    const int* __restrict__ fcur, int* __restrict__ fbase,
    int* __restrict__ rowptr)
{
    __shared__ int s[1024];
    int t = threadIdx.x;
    int v = 0;
    if (t < FB) {
        #pragma unroll
        for (int x = 0; x < NX; ++x) {
            int cell = x * FB + t;
            v += fcur[cell] - cell * BCAP_X;      // cell size
        }
    }
    s[t] = v;
    __syncthreads();
    for (int off = 1; off < 1024; off <<= 1) {
        int u = (t >= off) ? s[t - off] : 0;
        __syncthreads();
        s[t] += u;
        __syncthreads();
    }
    if (t < FB) fbase[t] = s[t] - v;
    if (t == FB - 1) {
        fbase[FB] = s[t];
        rowptr[N_NODES] = s[t];
    }
}

// Phase 2: one block per bucket. Stream the bucket's 8 XCD sub-segments into
// LDS + 100-counter histogram; tiny scan -> per-node rowptr AND local ranks;
// scatter into the bucket's contiguous ~12.8KB CSR slice (one block = one
// XCD = full-sector writebacks). No global atomics at all.
__global__ __launch_bounds__(256) void sort_kernel(
    const u64* __restrict__ stag, const int* __restrict__ fcur,
    const int* __restrict__ fbase, int* __restrict__ rowptr,
    int2* __restrict__ edges)
{
    __shared__ u64 ls[BCAP];       // 16 KB segment cache
    __shared__ int cnt[BN];
    __shared__ int cur[BN];
    __shared__ int sc[128];
    const int b = blockIdx.x;
    const int base = fbase[b];
    const int t = threadIdx.x;
    for (int i = t; i < BN; i += 256) cnt[i] = 0;
    __syncthreads();
    int ofs = 0;
    #pragma unroll
    for (int x = 0; x < NX; ++x) {
        int cell = x * FB + b;
        int sz = fcur[cell] - cell * BCAP_X;      // uniform scalar load
        const u64* sp = stag + (size_t)cell * BCAP_X;
        for (int i = t; i < sz; i += 256) {
            u64 r = __builtin_nontemporal_load(&sp[i]);
            ls[ofs + i] = r;
            atomicAdd(&cnt[((unsigned int)r) >> 17], 1);
        }
        ofs += sz;
    }
    const int size = ofs;
    __syncthreads();
    if (t < 128) sc[t] = (t < BN) ? cnt[t] : 0;
    __syncthreads();
    for (int off = 1; off < 128; off <<= 1) {
        int u = 0;
        if (t < 128 && t >= off) u = sc[t - off];
        __syncthreads();
        if (t < 128) sc[t] += u;
        __syncthreads();
    }
    if (t < BN) {
        int excl = sc[t] - cnt[t];
        rowptr[b * BN + t] = base + excl;
        cur[t] = excl;
    }
    __syncthreads();
    for (int i = t; i < size; i += 256) {
        u64 r = ls[i];
        unsigned int lo = (unsigned int)r;
        int dloc = lo >> 17;
        int rank = atomicAdd(&cur[dloc], 1);
        edges[base + rank] = make_int2((int)(lo & 0x1FFFFu),
                                       (int)(unsigned int)(r >> 32));
    }
}

// ======================= f32 -> bf16 convert (input x) =======================
__global__ __launch_bounds__(256) void f2bf_kernel(
    const float* __restrict__ in, u16* __restrict__ out)
{
    int i = blockIdx.x * 256 + threadIdx.x;   // one float4 per thread
    if (i >= (N_NODES * D) / 4) return;
    float4 v = ((const float4*)in)[i];
    ushort4 o;
    o.x = f2bf(v.x); o.y = f2bf(v.y); o.z = f2bf(v.z); o.w = f2bf(v.w);
    ((ushort4*)out)[i] = o;
}

// ================== Weight prep: W2T[l][n][k] bf16, k = [Wrel;Wroot] =========
__global__ __launch_bounds__(256) void wprep_kernel(
    const float* __restrict__ Wrel, const float* __restrict__ Wroot,
    u16* __restrict__ W2T)
{
    int i = blockIdx.x * 256 + threadIdx.x;  // over 5*64*128
    if (i >= N_LAYERS * 64 * 128) return;
    int l = i / (64 * 128);
    int rem = i % (64 * 128);
    int n = rem >> 7;   // out dim
    int k = rem & 127;  // input dim (0..63 = rel/agg, 64..127 = root/x)
    float v = (k < 64) ? Wrel[l * 4096 + k * 64 + n]
                       : Wroot[l * 4096 + (k - 64) * 64 + n];
    W2T[i] = f2bf(v);
}

// ========= Fused layer v5: edge-slot x dim-chunk gather (no shuffles) ========
// Rounds 9/11 failed because every variant kept the PER-EDGE BROADCAST
// structure (2 cross-lane ops/edge + divergent half-waves). v5 remaps:
// lane = (edge-slot lane>>3, dim-chunk lane&7). One 16B/lane wave load
// fetches 8 edges x full 128B rows = 1KB (4x fewer gather instrs); each lane
// loads its OWN edge record (8 lanes share an address -> 1-line broadcast);
// ZERO shfl/bpermute in the loop; whole wave serves one node -> trip counts
// wave-uniform, NO divergence. Tail killed by w=0 padding (invalid slots
// clamp to edges[0], weight 0). Static 4-group unroll (deg<=32; Poisson-16
// overflow ~1e-4 handled by rolled loop): all 8 gathers (2 nodes x 4) are
// issued before any consume -> 8KB in flight per wave. Per node: 8 f32
// partial accs/lane, then one 3-round shfl_xor(8/16/32) butterfly (sums the
// 8 edge-slot groups; lane&7 preserved); lanes 0-15 write both rows to the
// XOR-swizzled LDS tile. Phase B unchanged (HW-verified rounds 8-11).
#define GDECL2(N) uint4 N##h; float N##w
#define GLOAD2(N, bb, ee, gg) {                                             \
    int  ei_ = (bb) + (gg) * 8 + g8;                                        \
    bool v_  = ei_ < (ee);                                                  \
    int2 r_  = edges[v_ ? ei_ : 0];                                         \
    N##w = v_ ? __int_as_float(r_.y) : 0.f;                                 \
    int  s_  = v_ ? r_.x : 0;                                               \
    N##h = *(const uint4*)(hin + ((size_t)s_ << 6) + (size_t)k * 8); }
#define GCONS2(N, A) {                                                      \
    A[0] += bf2f_lo(N##h.x) * N##w;  A[1] += bf2f_hi(N##h.x) * N##w;        \
    A[2] += bf2f_lo(N##h.y) * N##w;  A[3] += bf2f_hi(N##h.y) * N##w;        \
    A[4] += bf2f_lo(N##h.z) * N##w;  A[5] += bf2f_hi(N##h.z) * N##w;        \
    A[6] += bf2f_lo(N##h.w) * N##w;  A[7] += bf2f_hi(N##h.w) * N##w; }

__global__ __launch_bounds__(512, 4) void layer_kernel(
    const u16* __restrict__ hin, const int* __restrict__ rowptr,
    const int2* __restrict__ edges, const u16* __restrict__ W2T,
    const float* __restrict__ brel,
    u16* __restrict__ hout_bf, float* __restrict__ hout_f32, int relu)
{
    __shared__ u16 aggs[16][64];      // 2KB [node][dim], rows XOR-swizzled
    const int wave = threadIdx.x >> 6;
    const int lane = threadIdx.x & 63;
    const int nb16 = blockIdx.x * 16;
    const int k    = lane & 7;        // dim chunk: dims 8k..8k+8
    const int g8   = lane >> 3;       // edge slot within an 8-edge group

    // ---- Phase A: this wave aggregates nodes n0 = nb16+2*wave and n0+1 ----
    {
        const int n0 = nb16 + 2 * wave;
        const int b0 = rowptr[n0];
        const int b1 = rowptr[n0 + 1];    // = e0
        const int e1 = rowptr[n0 + 2];
        const int ng0 = (b1 - b0 + 7) >> 3;
        const int ng1 = (e1 - b1 + 7) >> 3;

        float a0[8], a1[8];
        #pragma unroll
        for (int i = 0; i < 8; ++i) { a0[i] = 0.f; a1[i] = 0.f; }

        // Issue all 8 gathers (4 groups x 2 nodes) before any consume.
        GDECL2(p0); GDECL2(p1); GDECL2(p2); GDECL2(p3);
        GDECL2(q0); GDECL2(q1); GDECL2(q2); GDECL2(q3);
        GLOAD2(p0, b0, b1, 0); GLOAD2(q0, b1, e1, 0);
        GLOAD2(p1, b0, b1, 1); GLOAD2(q1, b1, e1, 1);
        GLOAD2(p2, b0, b1, 2); GLOAD2(q2, b1, e1, 2);
        GLOAD2(p3, b0, b1, 3); GLOAD2(q3, b1, e1, 3);
        GCONS2(p0, a0); GCONS2(q0, a1);
        GCONS2(p1, a0); GCONS2(q1, a1);
        if (ng0 > 2) GCONS2(p2, a0);      // uniform branches: skip padded
        if (ng1 > 2) GCONS2(q2, a1);      // groups' dead FMAs (w=0 anyway)
        if (ng0 > 3) GCONS2(p3, a0);
        if (ng1 > 3) GCONS2(q3, a1);
        if (ng0 > 4)                      // deg > 32: rare (Poisson 16)
            for (int g = 4; g < ng0; ++g) {
                GDECL2(t); GLOAD2(t, b0, b1, g); GCONS2(t, a0);
            }
        if (ng1 > 4)
            for (int g = 4; g < ng1; ++g) {
                GDECL2(u); GLOAD2(u, b1, e1, g); GCONS2(u, a1);
            }

        // Butterfly: sum the 8 edge-slot groups (lane&7 preserved by xor).
        #pragma unroll
        for (int i = 0; i < 8; ++i) {
            a0[i] += __shfl_xor(a0[i], 8);
            a0[i] += __shfl_xor(a0[i], 16);
            a0[i] += __shfl_xor(a0[i], 32);
            a1[i] += __shfl_xor(a1[i], 8);
            a1[i] += __shfl_xor(a1[i], 16);
            a1[i] += __shfl_xor(a1[i], 32);
        }

        // lanes 0-7: node0 chunk k; lanes 8-15: node1 chunk k (16B each)
        if (lane < 16) {
            int which = lane >> 3;
            int nl = 2 * wave + which;
            unsigned int pk[4];
            #pragma unroll
            for (int d = 0; d < 4; ++d) {
                float lo = which ? a1[2 * d]     : a0[2 * d];
                float hi = which ? a1[2 * d + 1] : a0[2 * d + 1];
                pk[d] = ((unsigned int)f2bf(hi) << 16) | f2bf(lo);
            }
            // dims 8k..8k+8 of row nl, XOR-swizzled (u16 units)
            int off = (nl << 6) + ((8 * k) ^ ((nl & 7) << 3));
            *(uint4*)(&aggs[0][0] + off) = make_uint4(pk[0], pk[1],
                                                      pk[2], pk[3]);
        }
    }
    __syncthreads();

    // ---- Phase B: waves 0-3, wave = n-tile. A = [agg ; hin_own] @ W2T + b --
    if (wave < 4) {
        const int nt = wave;
        const int m = lane & 15;   // node-in-tile for A; out-dim for B/D
        const int q = lane >> 4;   // quad

        bf16x8 a[4];
        {
            int r0 = (m << 6) | ((q * 8) ^ ((m & 7) << 3));        // dims 8q..
            int r1 = (m << 6) | ((32 + q * 8) ^ ((m & 7) << 3));   // 32+8q..
            a[0] = *(const bf16x8*)(&aggs[0][0] + r0);   // k  0..31 (agg)
            a[1] = *(const bf16x8*)(&aggs[0][0] + r1);   // k 32..63 (agg)
        }
        size_t rowa = (size_t)(nb16 + m) << 6;
        a[2] = *(const bf16x8*)(hin + rowa + q * 8);        // k 64..95 (x)
        a[3] = *(const bf16x8*)(hin + rowa + 32 + q * 8);   // k 96..127 (x)

        bf16x8 bfr[4];
        #pragma unroll
        for (int kk = 0; kk < 4; ++kk)
            bfr[kk] = *(const bf16x8*)(W2T + (size_t)(nt * 16 + m) * 128
                                       + kk * 32 + q * 8);

        float bv = brel[nt * 16 + m];
        f32x4 acc = (f32x4){bv, bv, bv, bv};
        #pragma unroll
        for (int kk = 0; kk < 4; ++kk)
            acc = __builtin_amdgcn_mfma_f32_16x16x32_bf16(a[kk], bfr[kk],
                                                          acc, 0, 0, 0);

        #pragma unroll
        for (int r = 0; r < 4; ++r) {
            int n2 = nb16 + q * 4 + r;           // node (row of D)
            float v = acc[r];
            if (relu) v = fmaxf(v, 0.f);
            int dim = nt * 16 + m;               // out dim (col of D)
            if (hout_f32) hout_f32[(size_t)n2 * 64 + dim] = v;
            else          hout_bf [(size_t)n2 * 64 + dim] = f2bf(v);
        }
    }
}

extern "C" void kernel_launch(void* const* d_in, const int* in_sizes, int n_in,
                              void* d_out, int out_size, void* d_ws, size_t ws_size,
                              hipStream_t stream)
{
    const float* x     = (const float*)d_in[0];
    const int*   ei    = (const int*)d_in[1];   // [2, E] int32
    const float* ew    = (const float*)d_in[2];
    const float* Wrel  = (const float*)d_in[3]; // [5, 64, 64]
    const float* brel  = (const float*)d_in[4]; // [5, 64]
    const float* Wroot = (const float*)d_in[5]; // [5, 64, 64]
    float* out = (float*)d_out;

    const int* src = ei;
    const int* dst = ei + N_EDGES;

    const size_t featb_bytes = (size_t)N_NODES * D * 2;  // 12.8 MB bf16
    char* ws = (char*)d_ws;
    size_t off = 0;
    u16*  hb     = (u16*)(ws + off);  off += featb_bytes;   // ping
    u16*  hb2    = (u16*)(ws + off);  off += featb_bytes;   // pong
    u16*  W2T    = (u16*)(ws + off);  off += (size_t)N_LAYERS * 64 * 128 * 2;
    int*  rowptr = (int*)(ws + off);  off += 400016;
    int*  fcur   = (int*)(ws + off);  off += NX * FB * 4;
    int*  fbase  = (int*)(ws + off);  off += (FB + 1) * 4 + 60;
    int2* edges  = (int2*)(ws + off); off += (size_t)N_EDGES * 8;

    // stag aliases hb+hb2 (8000 cells * 320 * 8B = 20.48MB < 25.6MB): live
    // only bin -> sort, both complete (stream-ordered) before f2bf writes hb.
    u64* stag = (u64*)ws;

    u16* hbuf[2] = {hb, hb2};

    const int cblocks = (N_NODES * D / 4 + 255) / 256;
    const int wblocks = (N_LAYERS * 64 * 128 + 255) / 256;  // 160
    const int lblocks = N_NODES / 16;                // 6250 (16 nodes/block)

    // ---- CSR build (counting sort) + converts ----
    initcur_kernel<<<8, 1024, 0, stream>>>(fcur);
    bin_kernel<<<BIN_BLOCKS, BIN_THREADS, 0, stream>>>(src, dst, ew, fcur, stag);
    fscan_kernel<<<1, 1024, 0, stream>>>(fcur, fbase, rowptr);
    sort_kernel<<<FB, 256, 0, stream>>>(stag, fcur, fbase, rowptr, edges);
    f2bf_kernel<<<cblocks, 256, 0, stream>>>(x, hb);
    wprep_kernel<<<wblocks, 256, 0, stream>>>(Wrel, Wroot, W2T);

    // ---- 5 fused GraphConv layers (ping-pong h buffers) ----
    for (int layer = 0; layer < N_LAYERS; ++layer) {
        int last = (layer == N_LAYERS - 1);
        layer_kernel<<<lblocks, 512, 0, stream>>>(
            hbuf[layer & 1], rowptr, edges,
            W2T + (size_t)layer * 64 * 128,
            brel + (size_t)layer * D,
            last ? nullptr : hbuf[(layer + 1) & 1],
            last ? out : nullptr,
            last ? 0 : 1);
    }
}